// Round 20
// baseline (170.073 us; speedup 1.0000x reference)
//
#include <hip/hip_runtime.h>

#define NB 2
#define NS 2048
#define ND 1024
#define NH 16
#define NDK 64
#define NM (NB*NS)   // 4096

typedef unsigned short u16;
typedef unsigned int u32;
typedef short bf16x8 __attribute__((ext_vector_type(8)));
typedef float f32x4 __attribute__((ext_vector_type(4)));
typedef const __attribute__((address_space(1))) void* gas_p;
typedef __attribute__((address_space(3))) void* las_p;

#define LOG2E 1.4426950408889634f
#define QSCALE (0.125f * LOG2E)

__device__ __forceinline__ u16 f2bf(float f) {
    unsigned u = __builtin_bit_cast(unsigned, f);
    u += 0x7fffu + ((u >> 16) & 1u);         // RTNE
    return (u16)(u >> 16);
}
__device__ __forceinline__ float bf2f(u16 h) {
    return __builtin_bit_cast(float, (unsigned)h << 16);
}
__device__ __forceinline__ u32 cvt_pk_bf16(float a, float b) {
    u32 r;
    asm("v_cvt_pk_bf16_f32 %0, %1, %2" : "=v"(r) : "v"(a), "v"(b));
    return r;   // [15:0]=bf16(a), [31:16]=bf16(b)
}

// ============ conv_all: fused input/weight conversion (hi planes only) ============
__global__ __launch_bounds__(256)
void conv_all(const float* __restrict__ xr, const float* __restrict__ xi,
              const float* __restrict__ W0, const float* __restrict__ W1,
              const float* __restrict__ W2, const float* __restrict__ W3,
              u16* __restrict__ XH, u16* __restrict__ WT)
{
    __shared__ float tls[64][68];
    const int tid = threadIdx.x;

    if (blockIdx.x < 8192) {
        const size_t gid = (size_t)blockIdx.x * 256 + tid;
        const size_t PQ = (size_t)NM * ND / 4;
        const int p = gid >= PQ;
        const size_t off = (gid - (p ? PQ : 0)) * 4;
        const float4 v = *(const float4*)&((p ? xi : xr)[off]);
        const size_t d = (size_t)p * NM * ND + off;
        float vs[4] = {v.x, v.y, v.z, v.w};
        ushort4 h;
        u16* hp = (u16*)&h;
        #pragma unroll
        for (int j = 0; j < 4; ++j) hp[j] = f2bf(vs[j]);
        *(ushort4*)&XH[d] = h;
        return;
    }

    const int bid2 = blockIdx.x - 8192;
    const int z = bid2 >> 8;
    const int rem = bid2 & 255;
    const int nt0 = (rem & 15) * 64;
    const int kt0 = ((rem >> 4) & 15) * 64;
    const float* W = z == 0 ? W0 : z == 1 ? W1 : z == 2 ? W2 : W3;
    u16* dh = WT + (size_t)z * 1048576;

    {
        const int kk = tid >> 4;
        const int nn = (tid & 15) * 4;
        #pragma unroll
        for (int i = 0; i < 4; ++i) {
            const float4 v = *(const float4*)&W[(size_t)(kt0 + kk + 16*i) * ND + nt0 + nn];
            tls[kk + 16*i][nn] = v.x; tls[kk + 16*i][nn+1] = v.y;
            tls[kk + 16*i][nn+2] = v.z; tls[kk + 16*i][nn+3] = v.w;
        }
    }
    __syncthreads();

    const int n  = tid >> 2;
    const int kc = (tid & 3) * 16;
    u16 hb[16];
    #pragma unroll
    for (int k = 0; k < 16; ++k) hb[k] = f2bf(tls[kc + k][n]);
    #pragma unroll
    for (int half = 0; half < 2; ++half)
        *(bf16x8*)&dh[(size_t)(nt0 + n) * ND + kt0 + kc + 8*half] = *(bf16x8*)&hb[8*half];
}

// ============ bf16 MFMA GEMM (1-term), 3-stage dbuf gld_lds pipeline (frozen) ============
template<int MODE, int NTHR>
__global__ __launch_bounds__(NTHR)
void gemm_bf(const u16* __restrict__ Ah, const u16* __restrict__ Bh,
             const float* __restrict__ b0, const float* __restrict__ b1,
             const float* __restrict__ b2,
             u16* __restrict__ Qr_, u16* __restrict__ Qi_,
             u16* __restrict__ Kr_, u16* __restrict__ Ki_,
             u16* __restrict__ Vt_, float* __restrict__ Yf)
{
    constexpr int NW  = NTHR / 64;
    constexpr int CPW = 16 / NW;
    constexpr int FM  = (NTHR == 256) ? 4 : 2;
    constexpr int WROW = FM * 16;
    __shared__ u16 LDS[3][2][4096];

    const int tid  = threadIdx.x;
    const int wave = tid >> 6;
    const int lane = tid & 63;
    const int g = lane >> 4;
    const int c = lane & 15;
    const int wm = wave >> 1;
    const int wn = wave & 1;

    const int nbx = gridDim.x;
    const int nwg = nbx * gridDim.y;
    const int wgid = blockIdx.y * nbx + blockIdx.x;
    const int swz = (wgid & 7) * (nwg >> 3) + (wgid >> 3);
    const int row0 = (swz / nbx) * 128;
    const int col0 = (swz % nbx) * 128;

    if constexpr (MODE == 0) {
        if (col0 >= 2048 && row0 >= 4096) return;   // V x imag: dead
    }

    const int lr = lane >> 2;
    const int lq = lane & 3;
    const u16* srcs[CPW];
    int doffs[CPW];
    #pragma unroll
    for (int i = 0; i < CPW; ++i) {
        const int ci = wave * CPW + i;
        const int p = ci >> 3;
        const int o = ci & 7;
        const u16* pl = p ? Bh : Ah;
        const int rb = p ? col0 : row0;
        srcs[i] = pl + (size_t)(rb + o*16 + lr) * ND + lq*8;
        doffs[i] = p*4096 + o*512;
    }

    f32x4 acc[FM][4];
    #pragma unroll
    for (int i = 0; i < FM; ++i)
        #pragma unroll
        for (int j = 0; j < 4; ++j)
            acc[i][j] = (f32x4){0.f, 0.f, 0.f, 0.f};

    #pragma unroll
    for (int i = 0; i < CPW; ++i)
        __builtin_amdgcn_global_load_lds((gas_p)srcs[i],
                                         (las_p)(&LDS[0][0][0] + doffs[i]), 16, 0, 0);
    #pragma unroll
    for (int i = 0; i < CPW; ++i)
        __builtin_amdgcn_global_load_lds((gas_p)(srcs[i] + 32),
                                         (las_p)(&LDS[1][0][0] + doffs[i]), 16, 0, 0);

    int cur = 0, nxt2 = 2;
    for (int t = 0; t < 32; ++t) {
        if (t < 30) {
            u16* ldst = &LDS[nxt2][0][0];
            #pragma unroll
            for (int i = 0; i < CPW; ++i)
                __builtin_amdgcn_global_load_lds((gas_p)(srcs[i] + (size_t)(t + 2) * 32),
                                                 (las_p)(ldst + doffs[i]), 16, 0, 0);
            if constexpr (CPW == 4) asm volatile("s_waitcnt vmcnt(8)" ::: "memory");
            else                    asm volatile("s_waitcnt vmcnt(4)" ::: "memory");
        } else if (t == 30) {
            if constexpr (CPW == 4) asm volatile("s_waitcnt vmcnt(4)" ::: "memory");
            else                    asm volatile("s_waitcnt vmcnt(2)" ::: "memory");
        } else {
            asm volatile("s_waitcnt vmcnt(0)" ::: "memory");
        }
        __builtin_amdgcn_sched_barrier(0);
        __builtin_amdgcn_s_barrier();
        __builtin_amdgcn_sched_barrier(0);

        const u16* AsH = &LDS[cur][0][0];
        const u16* BsH = &LDS[cur][1][0];

        bf16x8 a_h[FM], b_h[4];
        #pragma unroll
        for (int f = 0; f < FM; ++f)
            a_h[f] = *(const bf16x8*)&AsH[(wm*WROW + f*16 + c)*32 + 8*g];
        #pragma unroll
        for (int f = 0; f < 4; ++f)
            b_h[f] = *(const bf16x8*)&BsH[(wn*64 + f*16 + c)*32 + 8*g];

        __builtin_amdgcn_s_setprio(1);
        #pragma unroll
        for (int fm = 0; fm < FM; ++fm)
            #pragma unroll
            for (int fn = 0; fn < 4; ++fn)
                acc[fm][fn] = __builtin_amdgcn_mfma_f32_16x16x32_bf16(a_h[fm], b_h[fn], acc[fm][fn], 0, 0, 0);
        __builtin_amdgcn_s_setprio(0);
        __builtin_amdgcn_sched_barrier(0);
        __builtin_amdgcn_s_barrier();
        __builtin_amdgcn_sched_barrier(0);

        cur  = (cur  == 2) ? 0 : cur + 1;
        nxt2 = (nxt2 == 2) ? 0 : nxt2 + 1;
    }

    #pragma unroll
    for (int fm = 0; fm < FM; ++fm) {
        #pragma unroll
        for (int fn = 0; fn < 4; ++fn) {
            const int n = col0 + wn*64 + fn*16 + c;
            if constexpr (MODE == 0) {
                const int sel = n >> 10;
                const int nn = n & 1023;
                const int hh = nn >> 6;
                const int dk = nn & 63;
                if (sel == 2) {
                    const int m0 = row0 + wm*WROW + fm*16 + 4*g;
                    const int b  = m0 >> 11;
                    const int s  = m0 & (NS - 1);
                    const float bv = b2[nn];
                    uint2 pk;
                    pk.x = cvt_pk_bf16(acc[fm][fn][0] + bv, acc[fm][fn][1] + bv);
                    pk.y = cvt_pk_bf16(acc[fm][fn][2] + bv, acc[fm][fn][3] + bv);
                    *(uint2*)&Vt_[((size_t)(b*NH + hh) * NDK + dk) * NS + s] = pk;
                } else {
                    const float sc = sel ? 1.0f : QSCALE;
                    const float bb = (sel ? b1[nn] : b0[nn]) * sc;
                    #pragma unroll
                    for (int j = 0; j < 4; ++j) {
                        const int m = row0 + wm*WROW + fm*16 + 4*g + j;
                        const int plane = m >> 12;
                        const int mm = m & 4095;
                        const int b  = mm >> 11;
                        const int s  = mm & (NS - 1);
                        u16* dst = sel ? (plane ? Ki_ : Kr_) : (plane ? Qi_ : Qr_);
                        const float val = acc[fm][fn][j] * sc + (plane == 0 ? bb : 0.f);
                        dst[(((size_t)(b*NH + hh) * NS) + s) * NDK + dk] = f2bf(val);
                    }
                }
            } else {
                #pragma unroll
                for (int j = 0; j < 4; ++j) {
                    const int m = row0 + wm*WROW + fm*16 + 4*g + j;
                    Yf[(size_t)m * ND + n] = acc[fm][fn][j] + b0[n];
                }
            }
        }
    }
}

// ============ MFMA flash attention: KV-pair iteration (128 kv per barrier pair),
// K pair single-buffered (B1 trick), V pair double-buffered, Ps reused A->B ============
__global__ __launch_bounds__(512)
void attn_mfma(const u16* __restrict__ Qr, const u16* __restrict__ Qi,
               const u16* __restrict__ Kr, const u16* __restrict__ Ki,
               const u16* __restrict__ Vt, u16* __restrict__ OH)
{
    __shared__ __align__(16) u16 Ks[2][8192];      // [half][kv64][128], XOR-swz
    __shared__ __align__(16) u16 Vs[2][2][4096];   // [buf][half][dk64][64], XOR-swz
    __shared__ __align__(16) u16 Ps[8][1024];      // per-wave P[q16][kv64], XOR-swz

    const int tid  = threadIdx.x;
    const int wave = tid >> 6;      // 0..7
    const int lane = tid & 63;
    const int g = lane >> 4;
    const int c = lane & 15;

    const int nbx = gridDim.x;                  // 16
    const int nwg = nbx * gridDim.y;            // 512
    const int wgid = blockIdx.y * nbx + blockIdx.x;
    const int swz = (wgid & 7) * (nwg >> 3) + (wgid >> 3);
    const int bh = swz / nbx;
    const int q0 = (swz % nbx) * 128;
    const size_t base = (size_t)bh * NS * NDK;

    bf16x8 qb[4];
    {
        const u16* qr = Qr + base + (size_t)(q0 + wave*16 + c) * NDK;
        const u16* qi = Qi + base + (size_t)(q0 + wave*16 + c) * NDK;
        #pragma unroll
        for (int s = 0; s < 2; ++s) {
            qb[s] = *(const bf16x8*)(qr + 32*s + 8*g);
            const bf16x8 t = *(const bf16x8*)(qi + 32*s + 8*g);
            bf16x8 f;
            #pragma unroll
            for (int j = 0; j < 8; ++j) f[j] = t[j] ^ (short)0x8000;
            qb[2+s] = f;
        }
    }

    // staging maps (pre-swizzled global source + linear dest, rule #21)
    const int slot = lane & 15;
    const int rloc = lane >> 4;
    const u16* kplane = (slot < 8 ? Kr : Ki) + base;
    const u16* srcK[2];
    #pragma unroll
    for (int i = 0; i < 2; ++i) {
        const int row = (wave*2 + i)*4 + rloc;
        srcK[i] = kplane + (size_t)row * NDK + ((slot ^ (row & 7)) & 7) * 8;
    }
    const int r8 = lane >> 3, sl = lane & 7;
    const int dkw = wave*8 + r8;
    const u16* srcV = Vt + base + (size_t)dkw * NS + ((sl ^ r8) & 7) * 8;

    const int swzmask = (c & 7) << 4;
    int offKa[4], offPa[2], offPw[4];
    #pragma unroll
    for (int s = 0; s < 4; ++s) offKa[s] = c*256 + ((64*s + 16*g) ^ swzmask);
    #pragma unroll
    for (int s = 0; s < 2; ++s) offPa[s] = wave*2048 + c*128 + ((64*s + 16*g) ^ swzmask);
    #pragma unroll
    for (int nt = 0; nt < 4; ++nt) offPw[nt] = wave*2048 + c*128 + ((32*nt + 8*g) ^ swzmask);
    const int oV0 = c*128 + ((16*g) ^ swzmask);
    const int oV1 = oV0 ^ 64;

    f32x4 oacc[4];
    #pragma unroll
    for (int nt = 0; nt < 4; ++nt) oacc[nt] = (f32x4){0.f, 0.f, 0.f, 0.f};
    float lrun = 0.f;

    // prologue: stage pair 0 (K halves 0,1 ; V halves 0,1 -> buf 0)
    #pragma unroll
    for (int h = 0; h < 2; ++h) {
        #pragma unroll
        for (int i = 0; i < 2; ++i)
            __builtin_amdgcn_global_load_lds((gas_p)(srcK[i] + (size_t)(h*64) * NDK),
                                             (las_p)(&Ks[h][0] + (wave*2 + i)*512), 16, 0, 0);
        __builtin_amdgcn_global_load_lds((gas_p)(srcV + h*64),
                                         (las_p)(&Vs[0][h][0] + wave*512), 16, 0, 0);
    }
    asm volatile("s_waitcnt vmcnt(0)" ::: "memory");
    __builtin_amdgcn_sched_barrier(0);
    __builtin_amdgcn_s_barrier();
    __builtin_amdgcn_sched_barrier(0);

    #define NTP (NS/128)
    for (int pt = 0; pt < NTP; ++pt) {
        const int cur = pt & 1;

        // ---- QK^T both halves: sacc{A,B}[nt] = S[kv][q=c] ----
        f32x4 sa[4], sb[4];
        #pragma unroll
        for (int nt = 0; nt < 4; ++nt) {
            sa[nt] = (f32x4){0.f, 0.f, 0.f, 0.f};
            sb[nt] = (f32x4){0.f, 0.f, 0.f, 0.f};
        }
        __builtin_amdgcn_s_setprio(1);
        #pragma unroll
        for (int s = 0; s < 4; ++s) {
            #pragma unroll
            for (int nt = 0; nt < 4; ++nt) {
                const bf16x8 ka = *(const bf16x8*)((const char*)&Ks[0][0] + offKa[s] + nt*4096);
                sa[nt] = __builtin_amdgcn_mfma_f32_16x16x32_bf16(ka, qb[s], sa[nt], 0, 0, 0);
            }
        }
        #pragma unroll
        for (int s = 0; s < 4; ++s) {
            #pragma unroll
            for (int nt = 0; nt < 4; ++nt) {
                const bf16x8 kb = *(const bf16x8*)((const char*)&Ks[0][0] + 16384 + offKa[s] + nt*4096);
                sb[nt] = __builtin_amdgcn_mfma_f32_16x16x32_bf16(kb, qb[s], sb[nt], 0, 0, 0);
            }
        }
        __builtin_amdgcn_s_setprio(0);
        __builtin_amdgcn_sched_barrier(0);
        __builtin_amdgcn_s_barrier();       // B1: all waves done reading Ks pair
        __builtin_amdgcn_sched_barrier(0);

        // ---- issue next pair's loads (land during SM+PV of both halves) ----
        if (pt + 1 < NTP) {
            const int nk0 = (pt + 1) * 128;
            #pragma unroll
            for (int h = 0; h < 2; ++h) {
                #pragma unroll
                for (int i = 0; i < 2; ++i)
                    __builtin_amdgcn_global_load_lds((gas_p)(srcK[i] + (size_t)(nk0 + h*64) * NDK),
                                                     (las_p)(&Ks[h][0] + (wave*2 + i)*512), 16, 0, 0);
                __builtin_amdgcn_global_load_lds((gas_p)(srcV + nk0 + h*64),
                                                 (las_p)(&Vs[cur ^ 1][h][0] + wave*512), 16, 0, 0);
            }
        }

        // ---- half A: softmax + PV ----
        #pragma unroll
        for (int nt = 0; nt < 4; ++nt) {
            float p0 = __builtin_amdgcn_exp2f(sa[nt][0]);
            float p1 = __builtin_amdgcn_exp2f(sa[nt][1]);
            float p2 = __builtin_amdgcn_exp2f(sa[nt][2]);
            float p3 = __builtin_amdgcn_exp2f(sa[nt][3]);
            lrun += (p0 + p1) + (p2 + p3);
            uint2 pk;
            pk.x = cvt_pk_bf16(p0, p1);
            pk.y = cvt_pk_bf16(p2, p3);
            *(uint2*)((char*)&Ps[0][0] + offPw[nt]) = pk;
        }
        {
            const int vbase = (cur*2 + 0) << 13;     // Vs[cur][0] byte offset
            __builtin_amdgcn_s_setprio(1);
            #pragma unroll
            for (int s = 0; s < 2; ++s) {
                const bf16x8 pa = *(const bf16x8*)((const char*)&Ps[0][0] + offPa[s]);
                const int vbS = vbase + (s ? oV1 : oV0);
                #pragma unroll
                for (int nt = 0; nt < 4; ++nt) {
                    const bf16x8 vb = *(const bf16x8*)((const char*)&Vs[0][0][0] + vbS + nt*2048);
                    oacc[nt] = __builtin_amdgcn_mfma_f32_16x16x32_bf16(pa, vb, oacc[nt], 0, 0, 0);
                }
            }
            __builtin_amdgcn_s_setprio(0);
        }

        // ---- half B: softmax + PV (Ps reused; wave-local ordering) ----
        #pragma unroll
        for (int nt = 0; nt < 4; ++nt) {
            float p0 = __builtin_amdgcn_exp2f(sb[nt][0]);
            float p1 = __builtin_amdgcn_exp2f(sb[nt][1]);
            float p2 = __builtin_amdgcn_exp2f(sb[nt][2]);
            float p3 = __builtin_amdgcn_exp2f(sb[nt][3]);
            lrun += (p0 + p1) + (p2 + p3);
            uint2 pk;
            pk.x = cvt_pk_bf16(p0, p1);
            pk.y = cvt_pk_bf16(p2, p3);
            *(uint2*)((char*)&Ps[0][0] + offPw[nt]) = pk;
        }
        {
            const int vbase = (cur*2 + 1) << 13;     // Vs[cur][1] byte offset
            __builtin_amdgcn_s_setprio(1);
            #pragma unroll
            for (int s = 0; s < 2; ++s) {
                const bf16x8 pa = *(const bf16x8*)((const char*)&Ps[0][0] + offPa[s]);
                const int vbS = vbase + (s ? oV1 : oV0);
                #pragma unroll
                for (int nt = 0; nt < 4; ++nt) {
                    const bf16x8 vb = *(const bf16x8*)((const char*)&Vs[0][0][0] + vbS + nt*2048);
                    oacc[nt] = __builtin_amdgcn_mfma_f32_16x16x32_bf16(pa, vb, oacc[nt], 0, 0, 0);
                }
            }
            __builtin_amdgcn_s_setprio(0);
        }

        if (pt + 1 < NTP) {
            asm volatile("s_waitcnt vmcnt(0)" ::: "memory");   // next pair landed
            __builtin_amdgcn_sched_barrier(0);
            __builtin_amdgcn_s_barrier();   // B2
            __builtin_amdgcn_sched_barrier(0);
        }
    }

    lrun += __shfl_xor(lrun, 16, 64);
    lrun += __shfl_xor(lrun, 32, 64);
    const int b  = bh >> 4;
    const int hh = bh & 15;
    float linv[4];
    #pragma unroll
    for (int j = 0; j < 4; ++j) linv[j] = 1.0f / __shfl(lrun, 4*g + j, 64);
    #pragma unroll
    for (int j = 0; j < 4; ++j) {
        const int srow = q0 + wave*16 + 4*g + j;
        #pragma unroll
        for (int nt = 0; nt < 4; ++nt) {
            const size_t o = (size_t)(b*NS + srow)*ND + hh*NDK + nt*16 + c;
            OH[o] = f2bf(oacc[nt][j] * linv[j]);
        }
    }
}

extern "C" void kernel_launch(void* const* d_in, const int* in_sizes, int n_in,
                              void* d_out, int out_size, void* d_ws, size_t ws_size,
                              hipStream_t stream)
{
    const float* xr = (const float*)d_in[0];
    const float* xi = (const float*)d_in[1];
    const float* Wq = (const float*)d_in[2];
    const float* bq = (const float*)d_in[3];
    const float* Wk = (const float*)d_in[4];
    const float* bk = (const float*)d_in[5];
    const float* Wv = (const float*)d_in[6];
    const float* bv = (const float*)d_in[7];
    const float* Wo = (const float*)d_in[8];
    const float* bo = (const float*)d_in[9];
    float* out = (float*)d_out;

    u16* ws = (u16*)d_ws;
    const size_t PL = (size_t)NM * ND;           // 4,194,304 elems
    u16* XH = ws;                                 // stacked [xr;xi] hi, 2*PL
    u16* WT = ws + 2*PL;                          // hi planes q,k,v,o @ z*1M
    u16* QP = WT + 4 * 1048576;
    u16* Qr = QP;          u16* Qi = QP + PL;
    u16* Kr = QP + 2*PL;   u16* Ki = QP + 3*PL;
    u16* Vt = QP + 4*PL;                          // V^T [bh][dk][s]
    u16* OH = ws;                                 // alias dead XH region

    conv_all<<<8192 + 1024, 256, 0, stream>>>(xr, xi, Wq, Wk, Wv, Wo, XH, WT);

    // merged QKV projection (Q scaled by (1/8)*log2e in-epilogue)
    gemm_bf<0, 256><<<dim3(3*ND/128, 2*NM/128), 256, 0, stream>>>(
        XH, WT, bq, bk, bv, Qr, Qi, Kr, Ki, Vt, nullptr);

    attn_mfma<<<dim3(NS/128, NB*NH), 512, 0, stream>>>(Qr, Qi, Kr, Ki, Vt, OH);

    // final projection: 1-term bf16
    gemm_bf<1, 512><<<dim3(ND/128, NM/128), 512, 0, stream>>>(
        OH, WT + 3*1048576, bo, nullptr, nullptr,
        nullptr, nullptr, nullptr, nullptr, nullptr, out);
}

// Round 21
// 167.935 us; speedup vs baseline: 1.0127x; 1.0127x over previous
//
#include <hip/hip_runtime.h>

#define NB 2
#define NS 2048
#define ND 1024
#define NH 16
#define NDK 64
#define NM (NB*NS)   // 4096

typedef unsigned short u16;
typedef unsigned int u32;
typedef short bf16x8 __attribute__((ext_vector_type(8)));
typedef float f32x4 __attribute__((ext_vector_type(4)));
typedef const __attribute__((address_space(1))) void* gas_p;
typedef __attribute__((address_space(3))) void* las_p;

#define LOG2E 1.4426950408889634f
#define QSCALE (0.125f * LOG2E)

__device__ __forceinline__ u16 f2bf(float f) {
    unsigned u = __builtin_bit_cast(unsigned, f);
    u += 0x7fffu + ((u >> 16) & 1u);         // RTNE
    return (u16)(u >> 16);
}
__device__ __forceinline__ float bf2f(u16 h) {
    return __builtin_bit_cast(float, (unsigned)h << 16);
}
__device__ __forceinline__ u32 cvt_pk_bf16(float a, float b) {
    u32 r;
    asm("v_cvt_pk_bf16_f32 %0, %1, %2" : "=v"(r) : "v"(a), "v"(b));
    return r;   // [15:0]=bf16(a), [31:16]=bf16(b)
}

// ============ conv_all: fused input/weight conversion (hi planes only) ============
__global__ __launch_bounds__(256)
void conv_all(const float* __restrict__ xr, const float* __restrict__ xi,
              const float* __restrict__ W0, const float* __restrict__ W1,
              const float* __restrict__ W2, const float* __restrict__ W3,
              u16* __restrict__ XH, u16* __restrict__ WT)
{
    __shared__ float tls[64][68];
    const int tid = threadIdx.x;

    if (blockIdx.x < 8192) {
        const size_t gid = (size_t)blockIdx.x * 256 + tid;
        const size_t PQ = (size_t)NM * ND / 4;
        const int p = gid >= PQ;
        const size_t off = (gid - (p ? PQ : 0)) * 4;
        const float4 v = *(const float4*)&((p ? xi : xr)[off]);
        const size_t d = (size_t)p * NM * ND + off;
        float vs[4] = {v.x, v.y, v.z, v.w};
        ushort4 h;
        u16* hp = (u16*)&h;
        #pragma unroll
        for (int j = 0; j < 4; ++j) hp[j] = f2bf(vs[j]);
        *(ushort4*)&XH[d] = h;
        return;
    }

    const int bid2 = blockIdx.x - 8192;
    const int z = bid2 >> 8;
    const int rem = bid2 & 255;
    const int nt0 = (rem & 15) * 64;
    const int kt0 = ((rem >> 4) & 15) * 64;
    const float* W = z == 0 ? W0 : z == 1 ? W1 : z == 2 ? W2 : W3;
    u16* dh = WT + (size_t)z * 1048576;

    {
        const int kk = tid >> 4;
        const int nn = (tid & 15) * 4;
        #pragma unroll
        for (int i = 0; i < 4; ++i) {
            const float4 v = *(const float4*)&W[(size_t)(kt0 + kk + 16*i) * ND + nt0 + nn];
            tls[kk + 16*i][nn] = v.x; tls[kk + 16*i][nn+1] = v.y;
            tls[kk + 16*i][nn+2] = v.z; tls[kk + 16*i][nn+3] = v.w;
        }
    }
    __syncthreads();

    const int n  = tid >> 2;
    const int kc = (tid & 3) * 16;
    u16 hb[16];
    #pragma unroll
    for (int k = 0; k < 16; ++k) hb[k] = f2bf(tls[kc + k][n]);
    #pragma unroll
    for (int half = 0; half < 2; ++half)
        *(bf16x8*)&dh[(size_t)(nt0 + n) * ND + kt0 + kc + 8*half] = *(bf16x8*)&hb[8*half];
}

// ============ bf16 MFMA GEMM (1-term), pair-granularity dbuf pipeline ============
// Per iteration: issue next PAIR's loads (2 tiles in flight), one B1/B2 pair,
// 32 MFMA/wave (2 x 16 from the two staged buffers). 4 LDS buffers.
// MODE 0: merged QKV (256 thr). MODE 1: final projection (512 thr, fp32 out).
template<int MODE, int NTHR>
__global__ __launch_bounds__(NTHR)
void gemm_bf(const u16* __restrict__ Ah, const u16* __restrict__ Bh,
             const float* __restrict__ b0, const float* __restrict__ b1,
             const float* __restrict__ b2,
             u16* __restrict__ Qr_, u16* __restrict__ Qi_,
             u16* __restrict__ Kr_, u16* __restrict__ Ki_,
             u16* __restrict__ Vt_, float* __restrict__ Yf)
{
    constexpr int NW  = NTHR / 64;
    constexpr int CPW = 16 / NW;             // staging chunks per wave per tile
    constexpr int FM  = (NTHR == 256) ? 4 : 2;
    constexpr int WROW = FM * 16;
    __shared__ u16 LDS[4][2][4096];          // [buf][plane AH/BH][128*32]

    const int tid  = threadIdx.x;
    const int wave = tid >> 6;
    const int lane = tid & 63;
    const int g = lane >> 4;
    const int c = lane & 15;
    const int wm = wave >> 1;
    const int wn = wave & 1;

    const int nbx = gridDim.x;
    const int nwg = nbx * gridDim.y;
    const int wgid = blockIdx.y * nbx + blockIdx.x;
    const int swz = (wgid & 7) * (nwg >> 3) + (wgid >> 3);
    const int row0 = (swz / nbx) * 128;
    const int col0 = (swz % nbx) * 128;

    if constexpr (MODE == 0) {
        if (col0 >= 2048 && row0 >= 4096) return;   // V x imag: dead
    }

    const int lr = lane >> 2;
    const int lq = lane & 3;
    const u16* srcs[CPW];
    int doffs[CPW];
    #pragma unroll
    for (int i = 0; i < CPW; ++i) {
        const int ci = wave * CPW + i;
        const int p = ci >> 3;               // 0 AH, 1 BH
        const int o = ci & 7;
        const u16* pl = p ? Bh : Ah;
        const int rb = p ? col0 : row0;
        srcs[i] = pl + (size_t)(rb + o*16 + lr) * ND + lq*8;
        doffs[i] = p*4096 + o*512;
    }

    f32x4 acc[FM][4];
    #pragma unroll
    for (int i = 0; i < FM; ++i)
        #pragma unroll
        for (int j = 0; j < 4; ++j)
            acc[i][j] = (f32x4){0.f, 0.f, 0.f, 0.f};

    // prologue: stage pair 0 (tiles 0,1) into bufs 0,1
    #pragma unroll
    for (int q = 0; q < 2; ++q)
        #pragma unroll
        for (int i = 0; i < CPW; ++i)
            __builtin_amdgcn_global_load_lds((gas_p)(srcs[i] + (size_t)q * 32),
                                             (las_p)(&LDS[q][0][0] + doffs[i]), 16, 0, 0);

    for (int p = 0; p < 16; ++p) {           // 16 pairs = 32 k-tiles
        const int hb = (p & 1) * 2;          // buf base of current pair
        if (p < 15) {
            const int nb = ((p + 1) & 1) * 2;
            #pragma unroll
            for (int q = 0; q < 2; ++q)
                #pragma unroll
                for (int i = 0; i < CPW; ++i)
                    __builtin_amdgcn_global_load_lds(
                        (gas_p)(srcs[i] + (size_t)(2*(p + 1) + q) * 32),
                        (las_p)(&LDS[nb + q][0][0] + doffs[i]), 16, 0, 0);
            if constexpr (CPW == 4) asm volatile("s_waitcnt vmcnt(8)" ::: "memory");
            else                    asm volatile("s_waitcnt vmcnt(4)" ::: "memory");
        } else {
            asm volatile("s_waitcnt vmcnt(0)" ::: "memory");
        }
        __builtin_amdgcn_sched_barrier(0);
        __builtin_amdgcn_s_barrier();        // B1: current pair staged (all waves)
        __builtin_amdgcn_sched_barrier(0);

        #pragma unroll
        for (int q = 0; q < 2; ++q) {
            const u16* AsH = &LDS[hb + q][0][0];
            const u16* BsH = &LDS[hb + q][1][0];
            bf16x8 a_h[FM], b_h[4];
            #pragma unroll
            for (int f = 0; f < FM; ++f)
                a_h[f] = *(const bf16x8*)&AsH[(wm*WROW + f*16 + c)*32 + 8*g];
            #pragma unroll
            for (int f = 0; f < 4; ++f)
                b_h[f] = *(const bf16x8*)&BsH[(wn*64 + f*16 + c)*32 + 8*g];

            __builtin_amdgcn_s_setprio(1);
            #pragma unroll
            for (int fm = 0; fm < FM; ++fm)
                #pragma unroll
                for (int fn = 0; fn < 4; ++fn)
                    acc[fm][fn] = __builtin_amdgcn_mfma_f32_16x16x32_bf16(a_h[fm], b_h[fn], acc[fm][fn], 0, 0, 0);
            __builtin_amdgcn_s_setprio(0);
        }
        __builtin_amdgcn_sched_barrier(0);
        __builtin_amdgcn_s_barrier();        // B2: readers done before buf reuse
        __builtin_amdgcn_sched_barrier(0);
    }

    #pragma unroll
    for (int fm = 0; fm < FM; ++fm) {
        #pragma unroll
        for (int fn = 0; fn < 4; ++fn) {
            const int n = col0 + wn*64 + fn*16 + c;
            if constexpr (MODE == 0) {
                const int sel = n >> 10;          // 0 Q, 1 K, 2 V
                const int nn = n & 1023;
                const int hh = nn >> 6;
                const int dk = nn & 63;
                if (sel == 2) {
                    const int m0 = row0 + wm*WROW + fm*16 + 4*g;
                    const int b  = m0 >> 11;
                    const int s  = m0 & (NS - 1);
                    const float bv = b2[nn];
                    uint2 pk;
                    pk.x = cvt_pk_bf16(acc[fm][fn][0] + bv, acc[fm][fn][1] + bv);
                    pk.y = cvt_pk_bf16(acc[fm][fn][2] + bv, acc[fm][fn][3] + bv);
                    *(uint2*)&Vt_[((size_t)(b*NH + hh) * NDK + dk) * NS + s] = pk;
                } else {
                    const float sc = sel ? 1.0f : QSCALE;
                    const float bb = (sel ? b1[nn] : b0[nn]) * sc;
                    #pragma unroll
                    for (int j = 0; j < 4; ++j) {
                        const int m = row0 + wm*WROW + fm*16 + 4*g + j;
                        const int plane = m >> 12;
                        const int mm = m & 4095;
                        const int b  = mm >> 11;
                        const int s  = mm & (NS - 1);
                        u16* dst = sel ? (plane ? Ki_ : Kr_) : (plane ? Qi_ : Qr_);
                        const float val = acc[fm][fn][j] * sc + (plane == 0 ? bb : 0.f);
                        dst[(((size_t)(b*NH + hh) * NS) + s) * NDK + dk] = f2bf(val);
                    }
                }
            } else {
                #pragma unroll
                for (int j = 0; j < 4; ++j) {
                    const int m = row0 + wm*WROW + fm*16 + 4*g + j;
                    Yf[(size_t)m * ND + n] = acc[fm][fn][j] + b0[n];
                }
            }
        }
    }
}

// ============ MFMA flash attention (frozen r20 pair structure) ============
__global__ __launch_bounds__(512)
void attn_mfma(const u16* __restrict__ Qr, const u16* __restrict__ Qi,
               const u16* __restrict__ Kr, const u16* __restrict__ Ki,
               const u16* __restrict__ Vt, u16* __restrict__ OH)
{
    __shared__ __align__(16) u16 Ks[2][8192];      // [half][kv64][128], XOR-swz
    __shared__ __align__(16) u16 Vs[2][2][4096];   // [buf][half][dk64][64], XOR-swz
    __shared__ __align__(16) u16 Ps[8][1024];      // per-wave P[q16][kv64], XOR-swz

    const int tid  = threadIdx.x;
    const int wave = tid >> 6;      // 0..7
    const int lane = tid & 63;
    const int g = lane >> 4;
    const int c = lane & 15;

    const int nbx = gridDim.x;                  // 16
    const int nwg = nbx * gridDim.y;            // 512
    const int wgid = blockIdx.y * nbx + blockIdx.x;
    const int swz = (wgid & 7) * (nwg >> 3) + (wgid >> 3);
    const int bh = swz / nbx;
    const int q0 = (swz % nbx) * 128;
    const size_t base = (size_t)bh * NS * NDK;

    bf16x8 qb[4];
    {
        const u16* qr = Qr + base + (size_t)(q0 + wave*16 + c) * NDK;
        const u16* qi = Qi + base + (size_t)(q0 + wave*16 + c) * NDK;
        #pragma unroll
        for (int s = 0; s < 2; ++s) {
            qb[s] = *(const bf16x8*)(qr + 32*s + 8*g);
            const bf16x8 t = *(const bf16x8*)(qi + 32*s + 8*g);
            bf16x8 f;
            #pragma unroll
            for (int j = 0; j < 8; ++j) f[j] = t[j] ^ (short)0x8000;
            qb[2+s] = f;
        }
    }

    const int slot = lane & 15;
    const int rloc = lane >> 4;
    const u16* kplane = (slot < 8 ? Kr : Ki) + base;
    const u16* srcK[2];
    #pragma unroll
    for (int i = 0; i < 2; ++i) {
        const int row = (wave*2 + i)*4 + rloc;
        srcK[i] = kplane + (size_t)row * NDK + ((slot ^ (row & 7)) & 7) * 8;
    }
    const int r8 = lane >> 3, sl = lane & 7;
    const int dkw = wave*8 + r8;
    const u16* srcV = Vt + base + (size_t)dkw * NS + ((sl ^ r8) & 7) * 8;

    const int swzmask = (c & 7) << 4;
    int offKa[4], offPa[2], offPw[4];
    #pragma unroll
    for (int s = 0; s < 4; ++s) offKa[s] = c*256 + ((64*s + 16*g) ^ swzmask);
    #pragma unroll
    for (int s = 0; s < 2; ++s) offPa[s] = wave*2048 + c*128 + ((64*s + 16*g) ^ swzmask);
    #pragma unroll
    for (int nt = 0; nt < 4; ++nt) offPw[nt] = wave*2048 + c*128 + ((32*nt + 8*g) ^ swzmask);
    const int oV0 = c*128 + ((16*g) ^ swzmask);
    const int oV1 = oV0 ^ 64;

    f32x4 oacc[4];
    #pragma unroll
    for (int nt = 0; nt < 4; ++nt) oacc[nt] = (f32x4){0.f, 0.f, 0.f, 0.f};
    float lrun = 0.f;

    #pragma unroll
    for (int h = 0; h < 2; ++h) {
        #pragma unroll
        for (int i = 0; i < 2; ++i)
            __builtin_amdgcn_global_load_lds((gas_p)(srcK[i] + (size_t)(h*64) * NDK),
                                             (las_p)(&Ks[h][0] + (wave*2 + i)*512), 16, 0, 0);
        __builtin_amdgcn_global_load_lds((gas_p)(srcV + h*64),
                                         (las_p)(&Vs[0][h][0] + wave*512), 16, 0, 0);
    }
    asm volatile("s_waitcnt vmcnt(0)" ::: "memory");
    __builtin_amdgcn_sched_barrier(0);
    __builtin_amdgcn_s_barrier();
    __builtin_amdgcn_sched_barrier(0);

    #define NTP (NS/128)
    for (int pt = 0; pt < NTP; ++pt) {
        const int cur = pt & 1;

        f32x4 sa[4], sb[4];
        #pragma unroll
        for (int nt = 0; nt < 4; ++nt) {
            sa[nt] = (f32x4){0.f, 0.f, 0.f, 0.f};
            sb[nt] = (f32x4){0.f, 0.f, 0.f, 0.f};
        }
        __builtin_amdgcn_s_setprio(1);
        #pragma unroll
        for (int s = 0; s < 4; ++s) {
            #pragma unroll
            for (int nt = 0; nt < 4; ++nt) {
                const bf16x8 ka = *(const bf16x8*)((const char*)&Ks[0][0] + offKa[s] + nt*4096);
                sa[nt] = __builtin_amdgcn_mfma_f32_16x16x32_bf16(ka, qb[s], sa[nt], 0, 0, 0);
            }
        }
        #pragma unroll
        for (int s = 0; s < 4; ++s) {
            #pragma unroll
            for (int nt = 0; nt < 4; ++nt) {
                const bf16x8 kb = *(const bf16x8*)((const char*)&Ks[0][0] + 16384 + offKa[s] + nt*4096);
                sb[nt] = __builtin_amdgcn_mfma_f32_16x16x32_bf16(kb, qb[s], sb[nt], 0, 0, 0);
            }
        }
        __builtin_amdgcn_s_setprio(0);
        __builtin_amdgcn_sched_barrier(0);
        __builtin_amdgcn_s_barrier();       // B1
        __builtin_amdgcn_sched_barrier(0);

        if (pt + 1 < NTP) {
            const int nk0 = (pt + 1) * 128;
            #pragma unroll
            for (int h = 0; h < 2; ++h) {
                #pragma unroll
                for (int i = 0; i < 2; ++i)
                    __builtin_amdgcn_global_load_lds((gas_p)(srcK[i] + (size_t)(nk0 + h*64) * NDK),
                                                     (las_p)(&Ks[h][0] + (wave*2 + i)*512), 16, 0, 0);
                __builtin_amdgcn_global_load_lds((gas_p)(srcV + nk0 + h*64),
                                                 (las_p)(&Vs[cur ^ 1][h][0] + wave*512), 16, 0, 0);
            }
        }

        #pragma unroll
        for (int nt = 0; nt < 4; ++nt) {
            float p0 = __builtin_amdgcn_exp2f(sa[nt][0]);
            float p1 = __builtin_amdgcn_exp2f(sa[nt][1]);
            float p2 = __builtin_amdgcn_exp2f(sa[nt][2]);
            float p3 = __builtin_amdgcn_exp2f(sa[nt][3]);
            lrun += (p0 + p1) + (p2 + p3);
            uint2 pk;
            pk.x = cvt_pk_bf16(p0, p1);
            pk.y = cvt_pk_bf16(p2, p3);
            *(uint2*)((char*)&Ps[0][0] + offPw[nt]) = pk;
        }
        {
            const int vbase = (cur*2 + 0) << 13;
            __builtin_amdgcn_s_setprio(1);
            #pragma unroll
            for (int s = 0; s < 2; ++s) {
                const bf16x8 pa = *(const bf16x8*)((const char*)&Ps[0][0] + offPa[s]);
                const int vbS = vbase + (s ? oV1 : oV0);
                #pragma unroll
                for (int nt = 0; nt < 4; ++nt) {
                    const bf16x8 vb = *(const bf16x8*)((const char*)&Vs[0][0][0] + vbS + nt*2048);
                    oacc[nt] = __builtin_amdgcn_mfma_f32_16x16x32_bf16(pa, vb, oacc[nt], 0, 0, 0);
                }
            }
            __builtin_amdgcn_s_setprio(0);
        }

        #pragma unroll
        for (int nt = 0; nt < 4; ++nt) {
            float p0 = __builtin_amdgcn_exp2f(sb[nt][0]);
            float p1 = __builtin_amdgcn_exp2f(sb[nt][1]);
            float p2 = __builtin_amdgcn_exp2f(sb[nt][2]);
            float p3 = __builtin_amdgcn_exp2f(sb[nt][3]);
            lrun += (p0 + p1) + (p2 + p3);
            uint2 pk;
            pk.x = cvt_pk_bf16(p0, p1);
            pk.y = cvt_pk_bf16(p2, p3);
            *(uint2*)((char*)&Ps[0][0] + offPw[nt]) = pk;
        }
        {
            const int vbase = (cur*2 + 1) << 13;
            __builtin_amdgcn_s_setprio(1);
            #pragma unroll
            for (int s = 0; s < 2; ++s) {
                const bf16x8 pa = *(const bf16x8*)((const char*)&Ps[0][0] + offPa[s]);
                const int vbS = vbase + (s ? oV1 : oV0);
                #pragma unroll
                for (int nt = 0; nt < 4; ++nt) {
                    const bf16x8 vb = *(const bf16x8*)((const char*)&Vs[0][0][0] + vbS + nt*2048);
                    oacc[nt] = __builtin_amdgcn_mfma_f32_16x16x32_bf16(pa, vb, oacc[nt], 0, 0, 0);
                }
            }
            __builtin_amdgcn_s_setprio(0);
        }

        if (pt + 1 < NTP) {
            asm volatile("s_waitcnt vmcnt(0)" ::: "memory");
            __builtin_amdgcn_sched_barrier(0);
            __builtin_amdgcn_s_barrier();   // B2
            __builtin_amdgcn_sched_barrier(0);
        }
    }

    lrun += __shfl_xor(lrun, 16, 64);
    lrun += __shfl_xor(lrun, 32, 64);
    const int b  = bh >> 4;
    const int hh = bh & 15;
    float linv[4];
    #pragma unroll
    for (int j = 0; j < 4; ++j) linv[j] = 1.0f / __shfl(lrun, 4*g + j, 64);
    #pragma unroll
    for (int j = 0; j < 4; ++j) {
        const int srow = q0 + wave*16 + 4*g + j;
        #pragma unroll
        for (int nt = 0; nt < 4; ++nt) {
            const size_t o = (size_t)(b*NS + srow)*ND + hh*NDK + nt*16 + c;
            OH[o] = f2bf(oacc[nt][j] * linv[j]);
        }
    }
}

extern "C" void kernel_launch(void* const* d_in, const int* in_sizes, int n_in,
                              void* d_out, int out_size, void* d_ws, size_t ws_size,
                              hipStream_t stream)
{
    const float* xr = (const float*)d_in[0];
    const float* xi = (const float*)d_in[1];
    const float* Wq = (const float*)d_in[2];
    const float* bq = (const float*)d_in[3];
    const float* Wk = (const float*)d_in[4];
    const float* bk = (const float*)d_in[5];
    const float* Wv = (const float*)d_in[6];
    const float* bv = (const float*)d_in[7];
    const float* Wo = (const float*)d_in[8];
    const float* bo = (const float*)d_in[9];
    float* out = (float*)d_out;

    u16* ws = (u16*)d_ws;
    const size_t PL = (size_t)NM * ND;           // 4,194,304 elems
    u16* XH = ws;                                 // stacked [xr;xi] hi, 2*PL
    u16* WT = ws + 2*PL;                          // hi planes q,k,v,o @ z*1M
    u16* QP = WT + 4 * 1048576;
    u16* Qr = QP;          u16* Qi = QP + PL;
    u16* Kr = QP + 2*PL;   u16* Ki = QP + 3*PL;
    u16* Vt = QP + 4*PL;                          // V^T [bh][dk][s]
    u16* OH = ws;                                 // alias dead XH region

    conv_all<<<8192 + 1024, 256, 0, stream>>>(xr, xi, Wq, Wk, Wv, Wo, XH, WT);

    // merged QKV projection (Q scaled by (1/8)*log2e in-epilogue)
    gemm_bf<0, 256><<<dim3(3*ND/128, 2*NM/128), 256, 0, stream>>>(
        XH, WT, bq, bk, bv, Qr, Qi, Kr, Ki, Vt, nullptr);

    attn_mfma<<<dim3(NS/128, NB*NH), 512, 0, stream>>>(Qr, Qi, Kr, Ki, Vt, OH);

    // final projection: 1-term bf16
    gemm_bf<1, 512><<<dim3(ND/128, NM/128), 512, 0, stream>>>(
        OH, WT + 3*1048576, bo, nullptr, nullptr,
        nullptr, nullptr, nullptr, nullptr, nullptr, out);
}

// Round 22
// 167.795 us; speedup vs baseline: 1.0136x; 1.0008x over previous
//
#include <hip/hip_runtime.h>

#define NB 2
#define NS 2048
#define ND 1024
#define NH 16
#define NDK 64
#define NM (NB*NS)   // 4096

typedef unsigned short u16;
typedef unsigned int u32;
typedef short bf16x8 __attribute__((ext_vector_type(8)));
typedef float f32x4 __attribute__((ext_vector_type(4)));
typedef const __attribute__((address_space(1))) void* gas_p;
typedef __attribute__((address_space(3))) void* las_p;

#define LOG2E 1.4426950408889634f
#define QSCALE (0.125f * LOG2E)

__device__ __forceinline__ u16 f2bf(float f) {
    unsigned u = __builtin_bit_cast(unsigned, f);
    u += 0x7fffu + ((u >> 16) & 1u);         // RTNE
    return (u16)(u >> 16);
}
__device__ __forceinline__ float bf2f(u16 h) {
    return __builtin_bit_cast(float, (unsigned)h << 16);
}
__device__ __forceinline__ u32 cvt_pk_bf16(float a, float b) {
    u32 r;
    asm("v_cvt_pk_bf16_f32 %0, %1, %2" : "=v"(r) : "v"(a), "v"(b));
    return r;   // [15:0]=bf16(a), [31:16]=bf16(b)
}

// ============ conv_all: fused input/weight conversion (hi planes only) ============
__global__ __launch_bounds__(256)
void conv_all(const float* __restrict__ xr, const float* __restrict__ xi,
              const float* __restrict__ W0, const float* __restrict__ W1,
              const float* __restrict__ W2, const float* __restrict__ W3,
              u16* __restrict__ XH, u16* __restrict__ WT)
{
    __shared__ float tls[64][68];
    const int tid = threadIdx.x;

    if (blockIdx.x < 8192) {
        const size_t gid = (size_t)blockIdx.x * 256 + tid;
        const size_t PQ = (size_t)NM * ND / 4;
        const int p = gid >= PQ;
        const size_t off = (gid - (p ? PQ : 0)) * 4;
        const float4 v = *(const float4*)&((p ? xi : xr)[off]);
        const size_t d = (size_t)p * NM * ND + off;
        float vs[4] = {v.x, v.y, v.z, v.w};
        ushort4 h;
        u16* hp = (u16*)&h;
        #pragma unroll
        for (int j = 0; j < 4; ++j) hp[j] = f2bf(vs[j]);
        *(ushort4*)&XH[d] = h;
        return;
    }

    const int bid2 = blockIdx.x - 8192;
    const int z = bid2 >> 8;
    const int rem = bid2 & 255;
    const int nt0 = (rem & 15) * 64;
    const int kt0 = ((rem >> 4) & 15) * 64;
    const float* W = z == 0 ? W0 : z == 1 ? W1 : z == 2 ? W2 : W3;
    u16* dh = WT + (size_t)z * 1048576;

    {
        const int kk = tid >> 4;
        const int nn = (tid & 15) * 4;
        #pragma unroll
        for (int i = 0; i < 4; ++i) {
            const float4 v = *(const float4*)&W[(size_t)(kt0 + kk + 16*i) * ND + nt0 + nn];
            tls[kk + 16*i][nn] = v.x; tls[kk + 16*i][nn+1] = v.y;
            tls[kk + 16*i][nn+2] = v.z; tls[kk + 16*i][nn+3] = v.w;
        }
    }
    __syncthreads();

    const int n  = tid >> 2;
    const int kc = (tid & 3) * 16;
    u16 hb[16];
    #pragma unroll
    for (int k = 0; k < 16; ++k) hb[k] = f2bf(tls[kc + k][n]);
    #pragma unroll
    for (int half = 0; half < 2; ++half)
        *(bf16x8*)&dh[(size_t)(nt0 + n) * ND + kt0 + kc + 8*half] = *(bf16x8*)&hb[8*half];
}

// ============ bf16 MFMA GEMM (1-term), pair dbuf pipeline + LDS XOR-swizzle ============
// LDS tile [128][32] u16 (64B rows, 4x16B slots). Swizzle: slot ^= row&3
// (pre-swizzled global source + swizzled frag reads) -> 8-way conflict -> 4-way.
// MODE 0: merged QKV (256 thr). MODE 1: final projection (512 thr, fp32 out).
template<int MODE, int NTHR>
__global__ __launch_bounds__(NTHR)
void gemm_bf(const u16* __restrict__ Ah, const u16* __restrict__ Bh,
             const float* __restrict__ b0, const float* __restrict__ b1,
             const float* __restrict__ b2,
             u16* __restrict__ Qr_, u16* __restrict__ Qi_,
             u16* __restrict__ Kr_, u16* __restrict__ Ki_,
             u16* __restrict__ Vt_, float* __restrict__ Yf)
{
    constexpr int NW  = NTHR / 64;
    constexpr int CPW = 16 / NW;             // staging chunks per wave per tile
    constexpr int FM  = (NTHR == 256) ? 4 : 2;
    constexpr int WROW = FM * 16;
    __shared__ u16 LDS[4][2][4096];          // [buf][plane AH/BH][128*32]

    const int tid  = threadIdx.x;
    const int wave = tid >> 6;
    const int lane = tid & 63;
    const int g = lane >> 4;
    const int c = lane & 15;
    const int wm = wave >> 1;
    const int wn = wave & 1;

    const int nbx = gridDim.x;
    const int nwg = nbx * gridDim.y;
    const int wgid = blockIdx.y * nbx + blockIdx.x;
    const int swz = (wgid & 7) * (nwg >> 3) + (wgid >> 3);
    const int row0 = (swz / nbx) * 128;
    const int col0 = (swz % nbx) * 128;

    if constexpr (MODE == 0) {
        if (col0 >= 2048 && row0 >= 4096) return;   // V x imag: dead
    }

    // staging map: chunk = 16 rows x 64B; lane l -> row lr = l>>2, slot lq = l&3.
    // source pre-swizzled: slot' = lq ^ (lr&3)  (rule #21: write linear, read swz)
    const int lr = lane >> 2;
    const int lq = (lane & 3) ^ (lr & 3);
    const u16* srcs[CPW];
    int doffs[CPW];
    #pragma unroll
    for (int i = 0; i < CPW; ++i) {
        const int ci = wave * CPW + i;
        const int p = ci >> 3;               // 0 AH, 1 BH
        const int o = ci & 7;
        const u16* pl = p ? Bh : Ah;
        const int rb = p ? col0 : row0;
        srcs[i] = pl + (size_t)(rb + o*16 + lr) * ND + lq*8;
        doffs[i] = p*4096 + o*512;
    }

    f32x4 acc[FM][4];
    #pragma unroll
    for (int i = 0; i < FM; ++i)
        #pragma unroll
        for (int j = 0; j < 4; ++j)
            acc[i][j] = (f32x4){0.f, 0.f, 0.f, 0.f};

    // prologue: stage pair 0 (tiles 0,1) into bufs 0,1
    #pragma unroll
    for (int q = 0; q < 2; ++q)
        #pragma unroll
        for (int i = 0; i < CPW; ++i)
            __builtin_amdgcn_global_load_lds((gas_p)(srcs[i] + (size_t)q * 32),
                                             (las_p)(&LDS[q][0][0] + doffs[i]), 16, 0, 0);

    // swizzled fragment slot index (loop-invariant): g ^ (row&3) with row ≡ c mod 4
    const int gsA = (g ^ (c & 3)) * 8;

    for (int p = 0; p < 16; ++p) {           // 16 pairs = 32 k-tiles
        const int hb = (p & 1) * 2;          // buf base of current pair
        if (p < 15) {
            const int nb = ((p + 1) & 1) * 2;
            #pragma unroll
            for (int q = 0; q < 2; ++q)
                #pragma unroll
                for (int i = 0; i < CPW; ++i)
                    __builtin_amdgcn_global_load_lds(
                        (gas_p)(srcs[i] + (size_t)(2*(p + 1) + q) * 32),
                        (las_p)(&LDS[nb + q][0][0] + doffs[i]), 16, 0, 0);
            if constexpr (CPW == 4) asm volatile("s_waitcnt vmcnt(8)" ::: "memory");
            else                    asm volatile("s_waitcnt vmcnt(4)" ::: "memory");
        } else {
            asm volatile("s_waitcnt vmcnt(0)" ::: "memory");
        }
        __builtin_amdgcn_sched_barrier(0);
        __builtin_amdgcn_s_barrier();        // B1: current pair staged (all waves)
        __builtin_amdgcn_sched_barrier(0);

        #pragma unroll
        for (int q = 0; q < 2; ++q) {
            const u16* AsH = &LDS[hb + q][0][0];
            const u16* BsH = &LDS[hb + q][1][0];
            bf16x8 a_h[FM], b_h[4];
            #pragma unroll
            for (int f = 0; f < FM; ++f)
                a_h[f] = *(const bf16x8*)&AsH[(wm*WROW + f*16 + c)*32 + gsA];
            #pragma unroll
            for (int f = 0; f < 4; ++f)
                b_h[f] = *(const bf16x8*)&BsH[(wn*64 + f*16 + c)*32 + gsA];

            __builtin_amdgcn_s_setprio(1);
            #pragma unroll
            for (int fm = 0; fm < FM; ++fm)
                #pragma unroll
                for (int fn = 0; fn < 4; ++fn)
                    acc[fm][fn] = __builtin_amdgcn_mfma_f32_16x16x32_bf16(a_h[fm], b_h[fn], acc[fm][fn], 0, 0, 0);
            __builtin_amdgcn_s_setprio(0);
        }
        __builtin_amdgcn_sched_barrier(0);
        __builtin_amdgcn_s_barrier();        // B2: readers done before buf reuse
        __builtin_amdgcn_sched_barrier(0);
    }

    #pragma unroll
    for (int fm = 0; fm < FM; ++fm) {
        #pragma unroll
        for (int fn = 0; fn < 4; ++fn) {
            const int n = col0 + wn*64 + fn*16 + c;
            if constexpr (MODE == 0) {
                const int sel = n >> 10;          // 0 Q, 1 K, 2 V
                const int nn = n & 1023;
                const int hh = nn >> 6;
                const int dk = nn & 63;
                if (sel == 2) {
                    const int m0 = row0 + wm*WROW + fm*16 + 4*g;
                    const int b  = m0 >> 11;
                    const int s  = m0 & (NS - 1);
                    const float bv = b2[nn];
                    uint2 pk;
                    pk.x = cvt_pk_bf16(acc[fm][fn][0] + bv, acc[fm][fn][1] + bv);
                    pk.y = cvt_pk_bf16(acc[fm][fn][2] + bv, acc[fm][fn][3] + bv);
                    *(uint2*)&Vt_[((size_t)(b*NH + hh) * NDK + dk) * NS + s] = pk;
                } else {
                    const float sc = sel ? 1.0f : QSCALE;
                    const float bb = (sel ? b1[nn] : b0[nn]) * sc;
                    #pragma unroll
                    for (int j = 0; j < 4; ++j) {
                        const int m = row0 + wm*WROW + fm*16 + 4*g + j;
                        const int plane = m >> 12;
                        const int mm = m & 4095;
                        const int b  = mm >> 11;
                        const int s  = mm & (NS - 1);
                        u16* dst = sel ? (plane ? Ki_ : Kr_) : (plane ? Qi_ : Qr_);
                        const float val = acc[fm][fn][j] * sc + (plane == 0 ? bb : 0.f);
                        dst[(((size_t)(b*NH + hh) * NS) + s) * NDK + dk] = f2bf(val);
                    }
                }
            } else {
                #pragma unroll
                for (int j = 0; j < 4; ++j) {
                    const int m = row0 + wm*WROW + fm*16 + 4*g + j;
                    Yf[(size_t)m * ND + n] = acc[fm][fn][j] + b0[n];
                }
            }
        }
    }
}

// ============ MFMA flash attention (frozen r20 pair structure) ============
__global__ __launch_bounds__(512)
void attn_mfma(const u16* __restrict__ Qr, const u16* __restrict__ Qi,
               const u16* __restrict__ Kr, const u16* __restrict__ Ki,
               const u16* __restrict__ Vt, u16* __restrict__ OH)
{
    __shared__ __align__(16) u16 Ks[2][8192];      // [half][kv64][128], XOR-swz
    __shared__ __align__(16) u16 Vs[2][2][4096];   // [buf][half][dk64][64], XOR-swz
    __shared__ __align__(16) u16 Ps[8][1024];      // per-wave P[q16][kv64], XOR-swz

    const int tid  = threadIdx.x;
    const int wave = tid >> 6;      // 0..7
    const int lane = tid & 63;
    const int g = lane >> 4;
    const int c = lane & 15;

    const int nbx = gridDim.x;                  // 16
    const int nwg = nbx * gridDim.y;            // 512
    const int wgid = blockIdx.y * nbx + blockIdx.x;
    const int swz = (wgid & 7) * (nwg >> 3) + (wgid >> 3);
    const int bh = swz / nbx;
    const int q0 = (swz % nbx) * 128;
    const size_t base = (size_t)bh * NS * NDK;

    bf16x8 qb[4];
    {
        const u16* qr = Qr + base + (size_t)(q0 + wave*16 + c) * NDK;
        const u16* qi = Qi + base + (size_t)(q0 + wave*16 + c) * NDK;
        #pragma unroll
        for (int s = 0; s < 2; ++s) {
            qb[s] = *(const bf16x8*)(qr + 32*s + 8*g);
            const bf16x8 t = *(const bf16x8*)(qi + 32*s + 8*g);
            bf16x8 f;
            #pragma unroll
            for (int j = 0; j < 8; ++j) f[j] = t[j] ^ (short)0x8000;
            qb[2+s] = f;
        }
    }

    const int slot = lane & 15;
    const int rloc = lane >> 4;
    const u16* kplane = (slot < 8 ? Kr : Ki) + base;
    const u16* srcK[2];
    #pragma unroll
    for (int i = 0; i < 2; ++i) {
        const int row = (wave*2 + i)*4 + rloc;
        srcK[i] = kplane + (size_t)row * NDK + ((slot ^ (row & 7)) & 7) * 8;
    }
    const int r8 = lane >> 3, sl = lane & 7;
    const int dkw = wave*8 + r8;
    const u16* srcV = Vt + base + (size_t)dkw * NS + ((sl ^ r8) & 7) * 8;

    const int swzmask = (c & 7) << 4;
    int offKa[4], offPa[2], offPw[4];
    #pragma unroll
    for (int s = 0; s < 4; ++s) offKa[s] = c*256 + ((64*s + 16*g) ^ swzmask);
    #pragma unroll
    for (int s = 0; s < 2; ++s) offPa[s] = wave*2048 + c*128 + ((64*s + 16*g) ^ swzmask);
    #pragma unroll
    for (int nt = 0; nt < 4; ++nt) offPw[nt] = wave*2048 + c*128 + ((32*nt + 8*g) ^ swzmask);
    const int oV0 = c*128 + ((16*g) ^ swzmask);
    const int oV1 = oV0 ^ 64;

    f32x4 oacc[4];
    #pragma unroll
    for (int nt = 0; nt < 4; ++nt) oacc[nt] = (f32x4){0.f, 0.f, 0.f, 0.f};
    float lrun = 0.f;

    #pragma unroll
    for (int h = 0; h < 2; ++h) {
        #pragma unroll
        for (int i = 0; i < 2; ++i)
            __builtin_amdgcn_global_load_lds((gas_p)(srcK[i] + (size_t)(h*64) * NDK),
                                             (las_p)(&Ks[h][0] + (wave*2 + i)*512), 16, 0, 0);
        __builtin_amdgcn_global_load_lds((gas_p)(srcV + h*64),
                                         (las_p)(&Vs[0][h][0] + wave*512), 16, 0, 0);
    }
    asm volatile("s_waitcnt vmcnt(0)" ::: "memory");
    __builtin_amdgcn_sched_barrier(0);
    __builtin_amdgcn_s_barrier();
    __builtin_amdgcn_sched_barrier(0);

    #define NTP (NS/128)
    for (int pt = 0; pt < NTP; ++pt) {
        const int cur = pt & 1;

        f32x4 sa[4], sb[4];
        #pragma unroll
        for (int nt = 0; nt < 4; ++nt) {
            sa[nt] = (f32x4){0.f, 0.f, 0.f, 0.f};
            sb[nt] = (f32x4){0.f, 0.f, 0.f, 0.f};
        }
        __builtin_amdgcn_s_setprio(1);
        #pragma unroll
        for (int s = 0; s < 4; ++s) {
            #pragma unroll
            for (int nt = 0; nt < 4; ++nt) {
                const bf16x8 ka = *(const bf16x8*)((const char*)&Ks[0][0] + offKa[s] + nt*4096);
                sa[nt] = __builtin_amdgcn_mfma_f32_16x16x32_bf16(ka, qb[s], sa[nt], 0, 0, 0);
            }
        }
        #pragma unroll
        for (int s = 0; s < 4; ++s) {
            #pragma unroll
            for (int nt = 0; nt < 4; ++nt) {
                const bf16x8 kb = *(const bf16x8*)((const char*)&Ks[0][0] + 16384 + offKa[s] + nt*4096);
                sb[nt] = __builtin_amdgcn_mfma_f32_16x16x32_bf16(kb, qb[s], sb[nt], 0, 0, 0);
            }
        }
        __builtin_amdgcn_s_setprio(0);
        __builtin_amdgcn_sched_barrier(0);
        __builtin_amdgcn_s_barrier();       // B1
        __builtin_amdgcn_sched_barrier(0);

        if (pt + 1 < NTP) {
            const int nk0 = (pt + 1) * 128;
            #pragma unroll
            for (int h = 0; h < 2; ++h) {
                #pragma unroll
                for (int i = 0; i < 2; ++i)
                    __builtin_amdgcn_global_load_lds((gas_p)(srcK[i] + (size_t)(nk0 + h*64) * NDK),
                                                     (las_p)(&Ks[h][0] + (wave*2 + i)*512), 16, 0, 0);
                __builtin_amdgcn_global_load_lds((gas_p)(srcV + nk0 + h*64),
                                                 (las_p)(&Vs[cur ^ 1][h][0] + wave*512), 16, 0, 0);
            }
        }

        #pragma unroll
        for (int nt = 0; nt < 4; ++nt) {
            float p0 = __builtin_amdgcn_exp2f(sa[nt][0]);
            float p1 = __builtin_amdgcn_exp2f(sa[nt][1]);
            float p2 = __builtin_amdgcn_exp2f(sa[nt][2]);
            float p3 = __builtin_amdgcn_exp2f(sa[nt][3]);
            lrun += (p0 + p1) + (p2 + p3);
            uint2 pk;
            pk.x = cvt_pk_bf16(p0, p1);
            pk.y = cvt_pk_bf16(p2, p3);
            *(uint2*)((char*)&Ps[0][0] + offPw[nt]) = pk;
        }
        {
            const int vbase = (cur*2 + 0) << 13;
            __builtin_amdgcn_s_setprio(1);
            #pragma unroll
            for (int s = 0; s < 2; ++s) {
                const bf16x8 pa = *(const bf16x8*)((const char*)&Ps[0][0] + offPa[s]);
                const int vbS = vbase + (s ? oV1 : oV0);
                #pragma unroll
                for (int nt = 0; nt < 4; ++nt) {
                    const bf16x8 vb = *(const bf16x8*)((const char*)&Vs[0][0][0] + vbS + nt*2048);
                    oacc[nt] = __builtin_amdgcn_mfma_f32_16x16x32_bf16(pa, vb, oacc[nt], 0, 0, 0);
                }
            }
            __builtin_amdgcn_s_setprio(0);
        }

        #pragma unroll
        for (int nt = 0; nt < 4; ++nt) {
            float p0 = __builtin_amdgcn_exp2f(sb[nt][0]);
            float p1 = __builtin_amdgcn_exp2f(sb[nt][1]);
            float p2 = __builtin_amdgcn_exp2f(sb[nt][2]);
            float p3 = __builtin_amdgcn_exp2f(sb[nt][3]);
            lrun += (p0 + p1) + (p2 + p3);
            uint2 pk;
            pk.x = cvt_pk_bf16(p0, p1);
            pk.y = cvt_pk_bf16(p2, p3);
            *(uint2*)((char*)&Ps[0][0] + offPw[nt]) = pk;
        }
        {
            const int vbase = (cur*2 + 1) << 13;
            __builtin_amdgcn_s_setprio(1);
            #pragma unroll
            for (int s = 0; s < 2; ++s) {
                const bf16x8 pa = *(const bf16x8*)((const char*)&Ps[0][0] + offPa[s]);
                const int vbS = vbase + (s ? oV1 : oV0);
                #pragma unroll
                for (int nt = 0; nt < 4; ++nt) {
                    const bf16x8 vb = *(const bf16x8*)((const char*)&Vs[0][0][0] + vbS + nt*2048);
                    oacc[nt] = __builtin_amdgcn_mfma_f32_16x16x32_bf16(pa, vb, oacc[nt], 0, 0, 0);
                }
            }
            __builtin_amdgcn_s_setprio(0);
        }

        if (pt + 1 < NTP) {
            asm volatile("s_waitcnt vmcnt(0)" ::: "memory");
            __builtin_amdgcn_sched_barrier(0);
            __builtin_amdgcn_s_barrier();   // B2
            __builtin_amdgcn_sched_barrier(0);
        }
    }

    lrun += __shfl_xor(lrun, 16, 64);
    lrun += __shfl_xor(lrun, 32, 64);
    const int b  = bh >> 4;
    const int hh = bh & 15;
    float linv[4];
    #pragma unroll
    for (int j = 0; j < 4; ++j) linv[j] = 1.0f / __shfl(lrun, 4*g + j, 64);
    #pragma unroll
    for (int j = 0; j < 4; ++j) {
        const int srow = q0 + wave*16 + 4*g + j;
        #pragma unroll
        for (int nt = 0; nt < 4; ++nt) {
            const size_t o = (size_t)(b*NS + srow)*ND + hh*NDK + nt*16 + c;
            OH[o] = f2bf(oacc[nt][j] * linv[j]);
        }
    }
}

extern "C" void kernel_launch(void* const* d_in, const int* in_sizes, int n_in,
                              void* d_out, int out_size, void* d_ws, size_t ws_size,
                              hipStream_t stream)
{
    const float* xr = (const float*)d_in[0];
    const float* xi = (const float*)d_in[1];
    const float* Wq = (const float*)d_in[2];
    const float* bq = (const float*)d_in[3];
    const float* Wk = (const float*)d_in[4];
    const float* bk = (const float*)d_in[5];
    const float* Wv = (const float*)d_in[6];
    const float* bv = (const float*)d_in[7];
    const float* Wo = (const float*)d_in[8];
    const float* bo = (const float*)d_in[9];
    float* out = (float*)d_out;

    u16* ws = (u16*)d_ws;
    const size_t PL = (size_t)NM * ND;           // 4,194,304 elems
    u16* XH = ws;                                 // stacked [xr;xi] hi, 2*PL
    u16* WT = ws + 2*PL;                          // hi planes q,k,v,o @ z*1M
    u16* QP = WT + 4 * 1048576;
    u16* Qr = QP;          u16* Qi = QP + PL;
    u16* Kr = QP + 2*PL;   u16* Ki = QP + 3*PL;
    u16* Vt = QP + 4*PL;                          // V^T [bh][dk][s]
    u16* OH = ws;                                 // alias dead XH region

    conv_all<<<8192 + 1024, 256, 0, stream>>>(xr, xi, Wq, Wk, Wv, Wo, XH, WT);

    // merged QKV projection (Q scaled by (1/8)*log2e in-epilogue)
    gemm_bf<0, 256><<<dim3(3*ND/128, 2*NM/128), 256, 0, stream>>>(
        XH, WT, bq, bk, bv, Qr, Qi, Kr, Ki, Vt, nullptr);

    attn_mfma<<<dim3(NS/128, NB*NH), 512, 0, stream>>>(Qr, Qi, Kr, Ki, Vt, OH);

    // final projection: 1-term bf16
    gemm_bf<1, 512><<<dim3(ND/128, NM/128), 512, 0, stream>>>(
        OH, WT + 3*1048576, bo, nullptr, nullptr,
        nullptr, nullptr, nullptr, nullptr, nullptr, out);
}